// Round 6
// baseline (244.489 us; speedup 1.0000x reference)
//
#include <hip/hip_runtime.h>
#include <stdint.h>

// MFMA fragment types (gfx950)
typedef __attribute__((ext_vector_type(8))) short short8;  // 8 bf16 = 4 VGPRs
typedef __attribute__((ext_vector_type(4))) float f32x4;   // 4 fp32 acc / vec load

static_assert(sizeof(short8) == 16, "frag size");

__device__ __forceinline__ uint16_t f2bf(float f) {
  uint32_t u = __builtin_bit_cast(uint32_t, f);
  u += 0x7fffu + ((u >> 16) & 1u);
  return (uint16_t)(u >> 16);
}

__device__ __forceinline__ short8 pack_bf16x8(f32x4 lo, f32x4 hi) {
  union { uint32_t u[4]; short8 s; } z;
  z.u[0] = (uint32_t)f2bf(lo.x) | ((uint32_t)f2bf(lo.y) << 16);
  z.u[1] = (uint32_t)f2bf(lo.z) | ((uint32_t)f2bf(lo.w) << 16);
  z.u[2] = (uint32_t)f2bf(hi.x) | ((uint32_t)f2bf(hi.y) << 16);
  z.u[3] = (uint32_t)f2bf(hi.z) | ((uint32_t)f2bf(hi.w) << 16);
  return z.s;
}

__device__ __forceinline__ void gload_lds16(const void* g, void* lds_wave_base) {
  // async global->LDS, 16B/lane; LDS dst = wave-uniform base + lane*16
  __builtin_amdgcn_global_load_lds(
      (__attribute__((address_space(1))) void*)(void*)(g),
      (__attribute__((address_space(3))) void*)(lds_wave_base),
      16, 0, 0);
}

// Swizzle convention (bf16 staging): within each 64-elem K-group, 16B chunk c
// of row r stored at chunk c ^ (r&7). fp32 staging (A in main): same XOR on
// the low 3 bits of the 16B-chunk index within each 8-chunk (32-float... 8
// chunks = 32 fp32 = one 32-K slice pair) group; bank = (chunk*4)%32 is
// row-independent, so the XOR gives a full 8-way spread, rows r/r+8 2-way
// (free, m136).

// ---------------------------------------------------------------------------
// quant: dwT[o][i] = ternary(weight[i][o]) in {-1,0,+1} bf16, swizzled.
// ---------------------------------------------------------------------------
__global__ __launch_bounds__(256) void quant_kernel(const float* __restrict__ w,
                                                    uint16_t* __restrict__ dwT) {
  const int o = blockIdx.x, i = threadIdx.x;
  const float v = w[i * 256 + o];
  const float t = (v > 0.01f) ? 1.0f : ((v < -0.01f) ? -1.0f : 0.0f);
  dwT[o * 256 + (i ^ ((o & 7) << 3))] = f2bf(t);
}

// ---------------------------------------------------------------------------
// support (SINGLE-PASS K=256): spt[o][g] = bf16(0.01 * sum_i x[g][i]*tern[i][o])
// R0-proven version (unchanged): tile [64 g][64 o], 64 KB LDS, spt SWIZZLED.
// ---------------------------------------------------------------------------
#define SB_A 0       // [64 g][256 i] bf16 swizzled, 32768 B (reused in epilogue)
#define SB_B 32768   // [64 o][256 i] bf16 swizzled, 32768 B

__global__ __launch_bounds__(256) void support_kernel(const float* __restrict__ x,
                                                      const uint16_t* __restrict__ dwT,
                                                      uint16_t* __restrict__ spt) {
  __shared__ __align__(16) unsigned char smem[65536];
  const int t = threadIdx.x, lane = t & 63, w = t >> 6;
  const int r = lane & 15, q = lane >> 4;
  const int g0 = (blockIdx.x & 255) * 64;
  const int o0 = (blockIdx.x >> 8) * 64;

#pragma unroll
  for (int j = 0; j < 8; ++j) {
    const int id = j * 256 + t;              // 64 rows x 32 chunks = 2048 ids
    const int row = id >> 5, c = id & 31;
    const float* p = x + (size_t)(g0 + row) * 256 + c * 8;
    const f32x4 v0 = *(const f32x4*)p;
    const f32x4 v1 = *(const f32x4*)(p + 4);
    uint4 u;
    u.x = (uint32_t)f2bf(v0.x) | ((uint32_t)f2bf(v0.y) << 16);
    u.y = (uint32_t)f2bf(v0.z) | ((uint32_t)f2bf(v0.w) << 16);
    u.z = (uint32_t)f2bf(v1.x) | ((uint32_t)f2bf(v1.y) << 16);
    u.w = (uint32_t)f2bf(v1.z) | ((uint32_t)f2bf(v1.w) << 16);
    *(uint4*)(smem + SB_A + row * 512 + ((c ^ (row & 7)) << 4)) = u;
  }
#pragma unroll
  for (int j = 0; j < 8; ++j) {
    const int id = j * 256 + t, row = id >> 5, c = id & 31;
    gload_lds16(dwT + (size_t)(o0 + row) * 256 + c * 8,
                smem + SB_B + (size_t)(j * 256 + w * 64) * 16);
  }
  __syncthreads();

  f32x4 acc[4] = {};
#pragma unroll
  for (int h = 0; h < 8; ++h) {              // K=256 in 8 steps of 32
    short8 av, bv[4];
    const int pc = (((h * 4 + q) ^ (r & 7)) << 4);
    av = *(const short8*)(smem + SB_A + (16 * w + r) * 512 + pc);
#pragma unroll
    for (int ni = 0; ni < 4; ++ni)
      bv[ni] = *(const short8*)(smem + SB_B + (16 * ni + r) * 512 + pc);
#pragma unroll
    for (int ni = 0; ni < 4; ++ni)
      acc[ni] = __builtin_amdgcn_mfma_f32_16x16x32_bf16(av, bv[ni], acc[ni], 0, 0, 0);
  }
  __syncthreads();

  // epilogue: transpose buffer [64 o][64 g] bf16; XOR embeds the GLOBAL spt
  // swizzle (chunk c^(o&7) per 64-g group).
#pragma unroll
  for (int ni = 0; ni < 4; ++ni) {
    const int ol = 16 * ni + r;              // C col = o
#pragma unroll
    for (int reg = 0; reg < 4; ++reg) {
      const int gl = 16 * w + 4 * q + reg;   // C row = g
      const int gsw = gl ^ ((ol & 7) << 3);
      *(uint16_t*)(smem + (ol * 64 + gsw) * 2) = f2bf(acc[ni][reg] * 0.01f);
    }
  }
  __syncthreads();
#pragma unroll
  for (int it = 0; it < 2; ++it) {
    const int id = it * 256 + t, row = id >> 3, cc = id & 7;
    const uint4 u = *(const uint4*)(smem + (row * 64 + cc * 8) * 2);
    *(uint4*)(spt + (size_t)(o0 + row) * 16384 + g0 + cc * 8) = u;
  }
}

// ---------------------------------------------------------------------------
// main v7 (PURE-DMA K-loop): out = relu(adj @ spt + bias)
// Theory: R0-R5 all plateau at 77-80us because A's reg round-trip (load ->
// convert -> ds_write) entangles vmcnt with B's DMA and lgkm with frag reads,
// forcing full drains inside every step. Fix: BOTH operands via
// global_load_lds; A staged as RAW FP32 (converted at fragment read). The
// K-loop body then contains ONLY: 8 DMA-insts/wave (issued first, fly under
// compute) -> 12 ds_read + 8 MFMA -> one __syncthreads() (its vmcnt(0)+
// lgkmcnt(0)+s_barrier is exactly the per-step counted drain). 1 barrier/step.
// Tile [32 n][256 o], BK=64, 32 steps, dbuf 2x(8K A fp32 + 32K B bf16) =
// 80 KB -> 2 blocks/CU = 16 waves. Wave = [16 n][64 o], acc 16 VGPR.
// A-LDS [32 n][16 fp32-chunks]: LDS[row][c] = global chunk
// (c&8)|((c&7)^(row&7)) (inverse-swz source, linear DMA dest); frag read at
// chunk h*8 + ((2q+par)^(r&7)) -> conflict-free (2-way max).
// B = spt verbatim (swizzle embedded; 64-elem K-groups align with BK=64).
// ---------------------------------------------------------------------------
#define MA0 0u        // [32][256B] fp32, 8192 B
#define MA1 8192u
#define MBB0 16384u   // [256][128B] bf16 (spt pre-swizzled), 32768 B
#define MBB1 49152u

__global__ __launch_bounds__(512, 4) void gcn_main_kernel(const float* __restrict__ adj,
                                                          const uint16_t* __restrict__ spt,
                                                          const float* __restrict__ bias,
                                                          float* __restrict__ out) {
  __shared__ __align__(16) unsigned char smem[81920];
  const int t = threadIdx.x, lane = t & 63, wv = t >> 6;
  const int r = lane & 15, q = lane >> 4;
  const int nh = wv >> 2;                    // n-half (0/1)
  const int oq = wv & 3;                     // o-quarter
  const int bb = blockIdx.x & 7;             // batch -> XCD affinity (spt[bb] L2-resident)
  const int n0 = (blockIdx.x >> 3) * 32;     // n-tile
  const float* adjb = adj + ((size_t)bb * 2048 + n0) * 2048;
  const uint16_t* sptb = spt + (size_t)bb * 2048;

  // ---- A-DMA: 1 inst/wave/step. Wave wv covers rows 4wv..4wv+3 (1 KB).
  // lane l -> row 4wv + (l>>4), LDS chunk (l&15); global source chunk
  // inverse-swizzled.
  const int aRowD = 4 * wv + (lane >> 4);
  const int aCl = lane & 15;
  const int aCs = (aCl & 8) | ((aCl & 7) ^ (aRowD & 7));
  const float* aSrc = adjb + (size_t)aRowD * 2048 + aCs * 4;

  // ---- B-DMA: 4 insts/wave/step. Inst j covers rows (4wv+j)*8..+8 (1 KB).
  // lane l -> row +(l>>3), chunk (l&7); verbatim.
  const int bRowD = lane >> 3, bCl = lane & 7;

#define STAGE(K0, ABUF, BBUF)                                                  \
  do {                                                                         \
    gload_lds16(aSrc + (K0), smem + (ABUF) + (size_t)wv * 1024);               \
    _Pragma("unroll") for (int j = 0; j < 4; ++j) {                            \
      const int row_ = (4 * wv + j) * 8 + bRowD;                               \
      gload_lds16(sptb + (size_t)row_ * 16384 + (K0) + bCl * 8,                \
                  smem + (BBUF) + (size_t)(4 * wv + j) * 1024);                \
    }                                                                          \
  } while (0)

  f32x4 acc[4] = {};
  const int rr = r & 7;
  const unsigned aRowOff = (nh * 16 + r) * 256;     // my A row (fp32, 256 B)
  const unsigned bRowBase = (oq * 64) * 128;        // my o-quarter base

  STAGE(0, MA0, MBB0);
  __syncthreads();

  for (int kt = 0; kt < 32; ++kt) {
    const unsigned aCur = (kt & 1) ? MA1 : MA0;
    const unsigned bCur = (kt & 1) ? MBB1 : MBB0;
    const unsigned aNxt = (kt & 1) ? MA0 : MA1;
    const unsigned bNxt = (kt & 1) ? MBB0 : MBB1;

    if (kt < 31) STAGE((kt + 1) * 64, aNxt, bNxt);  // fly under compute

#pragma unroll
    for (int h = 0; h < 2; ++h) {            // 2 k-slices of 32
      const f32x4 a0 = *(const f32x4*)(smem + aCur + aRowOff +
                                       (h * 8 + ((2 * q) ^ rr)) * 16);
      const f32x4 a1 = *(const f32x4*)(smem + aCur + aRowOff +
                                       (h * 8 + ((2 * q + 1) ^ rr)) * 16);
      const short8 av = pack_bf16x8(a0, a1);
      const int pc = (((h * 4 + q) ^ rr) << 4);
      short8 bv[4];
#pragma unroll
      for (int ni = 0; ni < 4; ++ni)
        bv[ni] = *(const short8*)(smem + bCur + bRowBase + (16 * ni + r) * 128 + pc);
#pragma unroll
      for (int ni = 0; ni < 4; ++ni)
        acc[ni] = __builtin_amdgcn_mfma_f32_16x16x32_bf16(av, bv[ni], acc[ni], 0, 0, 0);
    }
    __syncthreads();   // vmcnt(0)+lgkmcnt(0)+barrier: drains next-step DMAs
  }

  // epilogue: +bias, relu, fp32 store
#pragma unroll
  for (int ni = 0; ni < 4; ++ni) {
    const int o = oq * 64 + 16 * ni + r;     // C col = N = o
    const float bs = bias[o];
#pragma unroll
    for (int reg = 0; reg < 4; ++reg) {
      const int n = n0 + nh * 16 + 4 * q + reg;  // C row = M = n
      out[((size_t)bb * 2048 + n) * 256 + o] = fmaxf(acc[ni][reg] + bs, 0.0f);
    }
  }
#undef STAGE
}

// ---------------------------------------------------------------------------
extern "C" void kernel_launch(void* const* d_in, const int* in_sizes, int n_in,
                              void* d_out, int out_size, void* d_ws, size_t ws_size,
                              hipStream_t stream) {
  const float* x      = (const float*)d_in[0];  // [8,2048,256]
  const float* adj    = (const float*)d_in[1];  // [8,2048,2048]
  const float* weight = (const float*)d_in[2];  // [256,256]
  const float* bias   = (const float*)d_in[3];  // [256]
  float* out = (float*)d_out;                   // [8,2048,256]

  uint16_t* dwT = (uint16_t*)d_ws;                          // 128 KB
  uint16_t* spt = (uint16_t*)((char*)d_ws + 131072);        // 8 MB

  hipLaunchKernelGGL(quant_kernel,    dim3(256),  dim3(256), 0, stream, weight, dwT);
  hipLaunchKernelGGL(support_kernel,  dim3(1024), dim3(256), 0, stream, x, dwT, spt);
  hipLaunchKernelGGL(gcn_main_kernel, dim3(512),  dim3(512), 0, stream, adj, spt, bias, out);
}

// Round 7
// 228.843 us; speedup vs baseline: 1.0684x; 1.0684x over previous
//
#include <hip/hip_runtime.h>
#include <stdint.h>

// MFMA fragment types (gfx950)
typedef __attribute__((ext_vector_type(8))) short short8;  // 8 bf16 = 4 VGPRs
typedef __attribute__((ext_vector_type(4))) float f32x4;   // 4 fp32 acc / vec load

static_assert(sizeof(short8) == 16, "frag size");

__device__ __forceinline__ uint16_t f2bf(float f) {
  uint32_t u = __builtin_bit_cast(uint32_t, f);
  u += 0x7fffu + ((u >> 16) & 1u);
  return (uint16_t)(u >> 16);
}

__device__ __forceinline__ short8 pack_bf16x8(f32x4 lo, f32x4 hi) {
  union { uint32_t u[4]; short8 s; } z;
  z.u[0] = (uint32_t)f2bf(lo.x) | ((uint32_t)f2bf(lo.y) << 16);
  z.u[1] = (uint32_t)f2bf(lo.z) | ((uint32_t)f2bf(lo.w) << 16);
  z.u[2] = (uint32_t)f2bf(hi.x) | ((uint32_t)f2bf(hi.y) << 16);
  z.u[3] = (uint32_t)f2bf(hi.z) | ((uint32_t)f2bf(hi.w) << 16);
  return z.s;
}

__device__ __forceinline__ void gload_lds16(const void* g, void* lds_wave_base) {
  // async global->LDS, 16B/lane; LDS dst = wave-uniform base + lane*16
  __builtin_amdgcn_global_load_lds(
      (__attribute__((address_space(1))) void*)(void*)(g),
      (__attribute__((address_space(3))) void*)(lds_wave_base),
      16, 0, 0);
}

#define MEMFENCE() asm volatile("" ::: "memory")

// ---------------------------------------------------------------------------
// quant: dwT[o][i] = ternary(weight[i][o]) in {-1,0,+1} bf16, swizzled.
// ---------------------------------------------------------------------------
__global__ __launch_bounds__(256) void quant_kernel(const float* __restrict__ w,
                                                    uint16_t* __restrict__ dwT) {
  const int o = blockIdx.x, i = threadIdx.x;
  const float v = w[i * 256 + o];
  const float t = (v > 0.01f) ? 1.0f : ((v < -0.01f) ? -1.0f : 0.0f);
  dwT[o * 256 + (i ^ ((o & 7) << 3))] = f2bf(t);
}

// ---------------------------------------------------------------------------
// support (SINGLE-PASS K=256): spt[o][g] = bf16(0.01 * sum_i x[g][i]*tern[i][o])
// R0-proven version (unchanged): tile [64 g][64 o], 64 KB LDS, spt SWIZZLED
// (chunk c^(o&7) within each 64-g group; main's B-DMA stages it verbatim).
// ---------------------------------------------------------------------------
#define SB_A 0       // [64 g][256 i] bf16 swizzled, 32768 B (reused in epilogue)
#define SB_B 32768   // [64 o][256 i] bf16 swizzled, 32768 B

__global__ __launch_bounds__(256) void support_kernel(const float* __restrict__ x,
                                                      const uint16_t* __restrict__ dwT,
                                                      uint16_t* __restrict__ spt) {
  __shared__ __align__(16) unsigned char smem[65536];
  const int t = threadIdx.x, lane = t & 63, w = t >> 6;
  const int r = lane & 15, q = lane >> 4;
  const int g0 = (blockIdx.x & 255) * 64;
  const int o0 = (blockIdx.x >> 8) * 64;

#pragma unroll
  for (int j = 0; j < 8; ++j) {
    const int id = j * 256 + t;              // 64 rows x 32 chunks = 2048 ids
    const int row = id >> 5, c = id & 31;
    const float* p = x + (size_t)(g0 + row) * 256 + c * 8;
    const f32x4 v0 = *(const f32x4*)p;
    const f32x4 v1 = *(const f32x4*)(p + 4);
    uint4 u;
    u.x = (uint32_t)f2bf(v0.x) | ((uint32_t)f2bf(v0.y) << 16);
    u.y = (uint32_t)f2bf(v0.z) | ((uint32_t)f2bf(v0.w) << 16);
    u.z = (uint32_t)f2bf(v1.x) | ((uint32_t)f2bf(v1.y) << 16);
    u.w = (uint32_t)f2bf(v1.z) | ((uint32_t)f2bf(v1.w) << 16);
    *(uint4*)(smem + SB_A + row * 512 + ((c ^ (row & 7)) << 4)) = u;
  }
#pragma unroll
  for (int j = 0; j < 8; ++j) {
    const int id = j * 256 + t, row = id >> 5, c = id & 31;
    gload_lds16(dwT + (size_t)(o0 + row) * 256 + c * 8,
                smem + SB_B + (size_t)(j * 256 + w * 64) * 16);
  }
  __syncthreads();

  f32x4 acc[4] = {};
#pragma unroll
  for (int h = 0; h < 8; ++h) {              // K=256 in 8 steps of 32
    short8 av, bv[4];
    const int pc = (((h * 4 + q) ^ (r & 7)) << 4);
    av = *(const short8*)(smem + SB_A + (16 * w + r) * 512 + pc);
#pragma unroll
    for (int ni = 0; ni < 4; ++ni)
      bv[ni] = *(const short8*)(smem + SB_B + (16 * ni + r) * 512 + pc);
#pragma unroll
    for (int ni = 0; ni < 4; ++ni)
      acc[ni] = __builtin_amdgcn_mfma_f32_16x16x32_bf16(av, bv[ni], acc[ni], 0, 0, 0);
  }
  __syncthreads();

  // epilogue: transpose buffer [64 o][64 g] bf16; XOR embeds the GLOBAL spt
  // swizzle (chunk c^(o&7) per 64-g group).
#pragma unroll
  for (int ni = 0; ni < 4; ++ni) {
    const int ol = 16 * ni + r;              // C col = o
#pragma unroll
    for (int reg = 0; reg < 4; ++reg) {
      const int gl = 16 * w + 4 * q + reg;   // C row = g
      const int gsw = gl ^ ((ol & 7) << 3);
      *(uint16_t*)(smem + (ol * 64 + gsw) * 2) = f2bf(acc[ni][reg] * 0.01f);
    }
  }
  __syncthreads();
#pragma unroll
  for (int it = 0; it < 2; ++it) {
    const int id = it * 256 + t, row = id >> 3, cc = id & 7;
    const uint4 u = *(const uint4*)(smem + (row * 64 + cc * 8) * 2);
    *(uint4*)(spt + (size_t)(o0 + row) * 16384 + g0 + cc * 8) = u;
  }
}

// ---------------------------------------------------------------------------
// main v8 (BM=64 + DEPTH-2 counted-vmcnt pure-DMA pipeline):
//   out = relu(adj @ spt + bias)
// Two changes vs the ~80us plateau kernels:
//  1. Tile [64 n][256 o] (BM 32->64): spt re-read 64x -> 32x; total staged
//     bytes 646 -> 390 MB. Grid 256 = 1 block/CU (LDS 144 KB).
//  2. Triple-buffered pure-DMA staging, stage(t+2) issued at step t, raw
//     s_barrier with s_waitcnt vmcnt(6) (keep exactly stage(t+2)'s 6 insts
//     in flight). Every stage gets TWO full steps to complete -> the
//     per-step latency exposure that R1/R2/R6 never removed is gone.
//     Loop body has zero non-DMA VMEM ops, so the count is exact.
// Wave = [32 n][64 o] (wn = wv>>2, oq = wv&3), acc[2][4] = 32 VGPR.
// Per step/wave: 6 DMA (2 A fp32 + 4 B), 16 ds_read, 16 MFMA, 1 barrier.
// A staged raw fp32 [64 n][256 B], source-chunk-swizzled (cs=(c&8)|((c&7)^
// (row&7))); read back at the inverse -> same pattern as R6 (accepted:
// R6 == R0 showed its conflicts are sub-dominant). B = spt verbatim
// (swizzle embedded, BK=64 aligns with the 64-g swizzle groups).
// ---------------------------------------------------------------------------
#define MBUF0 0u
#define MBUF1 49152u
#define MBUF2 98304u
#define MB_BOFF 16384u   // B region offset within a buffer (A: 16 KB, B: 32 KB)

__global__ __launch_bounds__(512, 2) void gcn_main_kernel(const float* __restrict__ adj,
                                                          const uint16_t* __restrict__ spt,
                                                          const float* __restrict__ bias,
                                                          float* __restrict__ out) {
  __shared__ __align__(16) unsigned char smem[147456];   // 3 x 48 KB
  const int t = threadIdx.x, lane = t & 63, wv = t >> 6;
  const int r = lane & 15, q = lane >> 4;
  const int wn = wv >> 2;                    // n-half (0/1): rows wn*32..+32
  const int oq = wv & 3;                     // o-quarter
  const int bb = blockIdx.x & 7;             // batch -> XCD affinity (spt[bb] L2-resident)
  const int n0 = (blockIdx.x >> 3) * 64;     // n-tile (32 tiles x 8 bb = 256 blocks)
  const float* adjb = adj + ((size_t)bb * 2048 + n0) * 2048;
  const uint16_t* sptb = spt + (size_t)bb * 2048;

  // ---- A-DMA (2 insts/wave/stage): inst j covers rows wv*8+j*4..+4
  // (4 rows x 256 B = 1 KB). lane -> row +(lane>>4), chunk lane&15; global
  // source chunk inverse-swizzled so LDS[row][c] = global chunk
  // (c&8)|((c&7)^(row&7)).
  const int aRow0 = wv * 8 + (lane >> 4);    // j=0 row
  const int aCl = lane & 15;
  const int aCs0 = (aCl & 8) | ((aCl & 7) ^ (aRow0 & 7));
  const int aCs1 = (aCl & 8) | ((aCl & 7) ^ ((aRow0 + 4) & 7));
  const float* aSrc0 = adjb + (size_t)aRow0 * 2048 + aCs0 * 4;
  const float* aSrc1 = adjb + (size_t)(aRow0 + 4) * 2048 + aCs1 * 4;
  const unsigned aDst0 = (unsigned)(wv * 2) * 1024u;
  const unsigned aDst1 = aDst0 + 1024u;

  // ---- B-DMA (4 insts/wave/stage): inst j covers rows (wv*4+j)*8..+8
  // (8 rows x 128 B = 1 KB), verbatim (spt pre-swizzled).
  const int bRowIn = lane >> 3, bCl = lane & 7;

#define STAGE(K0, BASE)                                                        \
  do {                                                                         \
    gload_lds16(aSrc0 + (K0), smem + (BASE) + aDst0);                          \
    gload_lds16(aSrc1 + (K0), smem + (BASE) + aDst1);                          \
    _Pragma("unroll") for (int j = 0; j < 4; ++j) {                            \
      const int row_ = (4 * wv + j) * 8 + bRowIn;                              \
      gload_lds16(sptb + (size_t)row_ * 16384 + (K0) + bCl * 8,                \
                  smem + (BASE) + MB_BOFF + (size_t)(4 * wv + j) * 1024);      \
    }                                                                          \
    MEMFENCE();                                                                \
  } while (0)

  f32x4 acc[2][4] = {};
  const int rr = r & 7;

  // prologue: stage steps 0,1 into buf0,buf1; publish buf0
  STAGE(0, MBUF0);
  STAGE(64, MBUF1);
  asm volatile("s_waitcnt vmcnt(6)" ::: "memory");   // drain stage0, keep stage1
  __builtin_amdgcn_s_barrier();

  unsigned bufCur = MBUF0, bufNxt = MBUF1, bufNxt2 = MBUF2;

  for (int kt = 0; kt < 32; ++kt) {
    if (kt < 30) STAGE((kt + 2) * 64, bufNxt2);      // 2 steps of slack

    // compute current step from bufCur
#pragma unroll
    for (int h = 0; h < 2; ++h) {            // 2 k-slices of 32
      short8 av[2], bv[4];
#pragma unroll
      for (int mi = 0; mi < 2; ++mi) {
        const int row = wn * 32 + mi * 16 + r;
        const int g0 = h * 8 + 2 * q;
        const int c0 = (g0 & 8) | ((g0 & 7) ^ (row & 7));
        const int c1 = (g0 & 8) | (((g0 + 1) & 7) ^ (row & 7));
        const f32x4 a0 = *(const f32x4*)(smem + bufCur + row * 256 + c0 * 16);
        const f32x4 a1 = *(const f32x4*)(smem + bufCur + row * 256 + c1 * 16);
        av[mi] = pack_bf16x8(a0, a1);
      }
      const int pc = (((h * 4 + q) ^ rr) << 4);
#pragma unroll
      for (int ni = 0; ni < 4; ++ni)
        bv[ni] = *(const short8*)(smem + bufCur + MB_BOFF +
                                  (oq * 64 + 16 * ni + r) * 128 + pc);
#pragma unroll
      for (int mi = 0; mi < 2; ++mi)
#pragma unroll
        for (int ni = 0; ni < 4; ++ni)
          acc[mi][ni] = __builtin_amdgcn_mfma_f32_16x16x32_bf16(av[mi], bv[ni],
                                                                acc[mi][ni], 0, 0, 0);
    }

    if (kt < 31) {
      if (kt < 30) {
        asm volatile("s_waitcnt vmcnt(6)" ::: "memory");  // drain stage(t+1), keep stage(t+2)
      } else {
        asm volatile("s_waitcnt vmcnt(0)" ::: "memory");  // tail: drain stage(31)
      }
      __builtin_amdgcn_s_barrier();
      const unsigned tmp = bufCur; bufCur = bufNxt; bufNxt = bufNxt2; bufNxt2 = tmp;
    }
  }

  // epilogue: +bias, relu, fp32 store
#pragma unroll
  for (int ni = 0; ni < 4; ++ni) {
    const int o = oq * 64 + 16 * ni + r;     // C col = N = o
    const float bs = bias[o];
#pragma unroll
    for (int mi = 0; mi < 2; ++mi)
#pragma unroll
      for (int reg = 0; reg < 4; ++reg) {
        const int n = n0 + wn * 32 + mi * 16 + 4 * q + reg;  // C row = M = n
        out[((size_t)bb * 2048 + n) * 256 + o] = fmaxf(acc[mi][ni][reg] + bs, 0.0f);
      }
  }
#undef STAGE
}

// ---------------------------------------------------------------------------
extern "C" void kernel_launch(void* const* d_in, const int* in_sizes, int n_in,
                              void* d_out, int out_size, void* d_ws, size_t ws_size,
                              hipStream_t stream) {
  const float* x      = (const float*)d_in[0];  // [8,2048,256]
  const float* adj    = (const float*)d_in[1];  // [8,2048,2048]
  const float* weight = (const float*)d_in[2];  // [256,256]
  const float* bias   = (const float*)d_in[3];  // [256]
  float* out = (float*)d_out;                   // [8,2048,256]

  uint16_t* dwT = (uint16_t*)d_ws;                          // 128 KB
  uint16_t* spt = (uint16_t*)((char*)d_ws + 131072);        // 8 MB

  hipLaunchKernelGGL(quant_kernel,    dim3(256),  dim3(256), 0, stream, weight, dwT);
  hipLaunchKernelGGL(support_kernel,  dim3(1024), dim3(256), 0, stream, x, dwT, spt);
  hipLaunchKernelGGL(gcn_main_kernel, dim3(256),  dim3(512), 0, stream, adj, spt, bias, out);
}